// Round 3
// baseline (1315.044 us; speedup 1.0000x reference)
//
// ============================================================================
// Round 3 (same plan as Round 2; prior round failed only due to prose being
// compiled into the file, so analysis now lives in this comment).
//
// Round 1 measured: PASS 1866 us. scatter_kernel x3 = 1486 us (80%): 496 us
// each, FETCH 419 MB / WRITE 409 MB, 1.67 TB/s combined = ~21% of HBM peak.
// Not BW-bound: WRITE 409 MB == 102.4M float atomics x 4B (atomics write
// through to coherent memory side), ~206 G atomics/s = serialization limit.
// GEMM 55 us/graph, degree/finalize minor.
//
// Change: replace atomic scatter with dst-grouped CSR gather.
//   degree (int for dst) -> single-block scan -> cursor fill -> SpMM as
//   gather with one 16-lane group per dst row, registers accumulate, each
//   out row written once. Finalize (rsqrt(deg_in)=f(row_start), +b, relu,
//   /3, accumulate into out) fused into SpMM epilogue; agg buffer deleted.
//
// Predicted counters: scatter (496us, F419/W409 MB) disappears. New
// spmm_fused: FETCH ~420 MB (same gather volume), WRITE ~13 MB (plain
// stores), 80-150 us/graph if fabric-BW-bound. New costs: scan ~15 us,
// fill ~40 us/graph. Total 1866 -> ~700-950 us. If spmm stays >=300 us at
// low BW it is latency-bound -> next lever is edge-locality, not atomics.
// ============================================================================
#include <hip/hip_runtime.h>

#define KDIM 128
#define NCOLS 64

// ---------------- degree: deg_out_f[src] += 1.0f ; deg_in_i[dst] += 1 -------
__global__ __launch_bounds__(256) void degree_kernel(
    const int* __restrict__ src, const int* __restrict__ dst,
    float* __restrict__ deg_out_f, int* __restrict__ deg_in_i, int E) {
  int e = blockIdx.x * 256 + threadIdx.x;
  if (e < E) {
    atomicAdd(&deg_out_f[src[e]], 1.0f);
    atomicAdd(&deg_in_i[dst[e]], 1);
  }
}

// ---------------- exclusive scan of deg_in_i -> row_start[N+1], cursor[N] ---
// Single block, 1024 threads, 4 elements/thread per 4096-chunk.
__global__ __launch_bounds__(1024) void scan_kernel(
    const int* __restrict__ deg, int* __restrict__ row_start,
    int* __restrict__ cursor, int N) {
  __shared__ int sdata[1024];
  __shared__ int carry_s;
  const int t = threadIdx.x;
  if (t == 0) carry_s = 0;
  __syncthreads();
  for (int base = 0; base < N; base += 4096) {
    int i0 = base + t * 4;
    int v[4];
    #pragma unroll
    for (int j = 0; j < 4; ++j) {
      int idx = i0 + j;
      v[j] = (idx < N) ? deg[idx] : 0;
    }
    int local = v[0] + v[1] + v[2] + v[3];
    sdata[t] = local;
    __syncthreads();
    for (int off = 1; off < 1024; off <<= 1) {
      int add = (t >= off) ? sdata[t - off] : 0;
      __syncthreads();
      sdata[t] += add;
      __syncthreads();
    }
    int excl_thread = carry_s + sdata[t] - local;
    int total = carry_s + sdata[1023];
    __syncthreads();
    int run = excl_thread;
    #pragma unroll
    for (int j = 0; j < 4; ++j) {
      int idx = i0 + j;
      if (idx < N) { row_start[idx] = run; cursor[idx] = run; }
      run += v[j];
    }
    if (t == 0) carry_s = total;
    __syncthreads();
  }
  if (t == 0) row_start[N] = carry_s;
}

// ---------------- CSR fill: csr_src[cursor[dst[e]]++] = src[e] --------------
__global__ __launch_bounds__(256) void fill_kernel(
    const int* __restrict__ src, const int* __restrict__ dst,
    int* __restrict__ cursor, int* __restrict__ csr_src, int E) {
  int e = blockIdx.x * 256 + threadIdx.x;
  if (e < E) {
    int pos = atomicAdd(&cursor[dst[e]], 1);
    csr_src[pos] = src[e];
  }
}

// ---------------- x = (h @ W) * rsqrt(max(deg_out,1)) -----------------------
__device__ __forceinline__ void fma4(float4& a, float s, const float4& b) {
  a.x = fmaf(s, b.x, a.x);
  a.y = fmaf(s, b.y, a.y);
  a.z = fmaf(s, b.z, a.z);
  a.w = fmaf(s, b.w, a.w);
}

__global__ __launch_bounds__(256) void gemm_scale_kernel(
    const float* __restrict__ h, const float* __restrict__ W,
    const float* __restrict__ deg_out, float* __restrict__ x, int N) {
  __shared__ float Ws[KDIM * NCOLS];     // 32 KB, [k][c]
  __shared__ float Hs[64][KDIM + 4];

  const int t = threadIdx.x;
  const int tx = t & 15;
  const int ty = t >> 4;
  const int row0 = blockIdx.x * 64;

  #pragma unroll
  for (int i = 0; i < 8; ++i) {
    int lin = i * 1024 + t * 4;
    *(float4*)&Ws[lin] = *(const float4*)&W[lin];
  }
  #pragma unroll
  for (int i = 0; i < 8; ++i) {
    int lin = i * 1024 + t * 4;
    int r = lin >> 7;
    int k = lin & 127;
    int row = row0 + r;
    float4 v = make_float4(0.f, 0.f, 0.f, 0.f);
    if (row < N) v = *(const float4*)&h[(size_t)row * KDIM + k];
    *(float4*)&Hs[r][k] = v;
  }
  __syncthreads();

  float4 acc0 = make_float4(0,0,0,0), acc1 = acc0, acc2 = acc0, acc3 = acc0;
  #pragma unroll 4
  for (int k = 0; k < KDIM; k += 4) {
    float4 a0 = *(float4*)&Hs[4 * ty + 0][k];
    float4 a1 = *(float4*)&Hs[4 * ty + 1][k];
    float4 a2 = *(float4*)&Hs[4 * ty + 2][k];
    float4 a3 = *(float4*)&Hs[4 * ty + 3][k];
    float4 w0 = *(float4*)&Ws[(k + 0) * NCOLS + 4 * tx];
    float4 w1 = *(float4*)&Ws[(k + 1) * NCOLS + 4 * tx];
    float4 w2 = *(float4*)&Ws[(k + 2) * NCOLS + 4 * tx];
    float4 w3 = *(float4*)&Ws[(k + 3) * NCOLS + 4 * tx];
    fma4(acc0, a0.x, w0); fma4(acc0, a0.y, w1); fma4(acc0, a0.z, w2); fma4(acc0, a0.w, w3);
    fma4(acc1, a1.x, w0); fma4(acc1, a1.y, w1); fma4(acc1, a1.z, w2); fma4(acc1, a1.w, w3);
    fma4(acc2, a2.x, w0); fma4(acc2, a2.y, w1); fma4(acc2, a2.z, w2); fma4(acc2, a2.w, w3);
    fma4(acc3, a3.x, w0); fma4(acc3, a3.y, w1); fma4(acc3, a3.z, w2); fma4(acc3, a3.w, w3);
  }

  float4 accs[4] = {acc0, acc1, acc2, acc3};
  #pragma unroll
  for (int r = 0; r < 4; ++r) {
    int row = row0 + 4 * ty + r;
    if (row < N) {
      float s = rsqrtf(fmaxf(deg_out[row], 1.0f));
      float4 o;
      o.x = accs[r].x * s; o.y = accs[r].y * s;
      o.z = accs[r].z * s; o.w = accs[r].w * s;
      *(float4*)&x[(size_t)row * NCOLS + 4 * tx] = o;
    }
  }
}

// ---------------- fused SpMM gather + finalize ------------------------------
// 16 threads per dst row; out[d] += relu(sum_{s in in(d)} x[s]*rsqrt(deg)+b)/3
__global__ __launch_bounds__(256) void spmm_fused_kernel(
    const int* __restrict__ row_start, const int* __restrict__ csr_src,
    const float* __restrict__ x, const float* __restrict__ b,
    float* __restrict__ out, int N) {
  int gid = blockIdx.x * 256 + threadIdx.x;
  int d = gid >> 4;
  int q = (gid & 15) * 4;
  if (d >= N) return;
  int i = row_start[d];
  const int iend = row_start[d + 1];
  const int deg = iend - i;

  float4 acc = make_float4(0.f, 0.f, 0.f, 0.f);
  for (; i + 3 < iend; i += 4) {
    int sa = csr_src[i + 0];
    int sb = csr_src[i + 1];
    int sc = csr_src[i + 2];
    int sd = csr_src[i + 3];
    float4 va = *(const float4*)&x[(size_t)sa * NCOLS + q];
    float4 vb = *(const float4*)&x[(size_t)sb * NCOLS + q];
    float4 vc = *(const float4*)&x[(size_t)sc * NCOLS + q];
    float4 vd = *(const float4*)&x[(size_t)sd * NCOLS + q];
    acc.x += va.x + vb.x + vc.x + vd.x;
    acc.y += va.y + vb.y + vc.y + vd.y;
    acc.z += va.z + vb.z + vc.z + vd.z;
    acc.w += va.w + vb.w + vc.w + vd.w;
  }
  for (; i < iend; ++i) {
    int s = csr_src[i];
    float4 v = *(const float4*)&x[(size_t)s * NCOLS + q];
    acc.x += v.x; acc.y += v.y; acc.z += v.z; acc.w += v.w;
  }

  float sc = rsqrtf(fmaxf((float)deg, 1.0f));
  float4 bb = *(const float4*)&b[q];
  float4 cur = *(float4*)&out[(size_t)d * NCOLS + q];
  cur.x += fmaxf(fmaf(acc.x, sc, bb.x), 0.f) * (1.0f / 3.0f);
  cur.y += fmaxf(fmaf(acc.y, sc, bb.y), 0.f) * (1.0f / 3.0f);
  cur.z += fmaxf(fmaf(acc.z, sc, bb.z), 0.f) * (1.0f / 3.0f);
  cur.w += fmaxf(fmaf(acc.w, sc, bb.w), 0.f) * (1.0f / 3.0f);
  *(float4*)&out[(size_t)d * NCOLS + q] = cur;
}

extern "C" void kernel_launch(void* const* d_in, const int* in_sizes, int n_in,
                              void* d_out, int out_size, void* d_ws, size_t ws_size,
                              hipStream_t stream) {
  const float* h = (const float*)d_in[0];
  const int N = in_sizes[0] / KDIM;   // 50000
  float* out = (float*)d_out;

  // ws layout: x[N*64] | deg_out_f[N] | deg_in_i[N] | row_start[N+4] |
  //            cursor[N] | csr_src[E]
  float* x         = (float*)d_ws;
  float* deg_out_f = x + (size_t)N * NCOLS;
  int*   deg_in_i  = (int*)(deg_out_f + N);
  int*   row_start = deg_in_i + N;
  int*   cursor    = row_start + N + 4;
  int*   csr_src   = cursor + N;

  hipMemsetAsync(d_out, 0, (size_t)N * NCOLS * sizeof(float), stream);

  for (int g = 0; g < 3; ++g) {
    const int*   src = (const int*)  d_in[1 + g * 4];
    const int*   dst = (const int*)  d_in[2 + g * 4];
    const float* W   = (const float*)d_in[3 + g * 4];
    const float* b   = (const float*)d_in[4 + g * 4];
    const int E = in_sizes[1 + g * 4];

    hipMemsetAsync(deg_out_f, 0, (size_t)2 * N * sizeof(int), stream);

    degree_kernel<<<(E + 255) / 256, 256, 0, stream>>>(src, dst, deg_out_f, deg_in_i, E);
    scan_kernel<<<1, 1024, 0, stream>>>(deg_in_i, row_start, cursor, N);
    fill_kernel<<<(E + 255) / 256, 256, 0, stream>>>(src, dst, cursor, csr_src, E);
    gemm_scale_kernel<<<(N + 63) / 64, 256, 0, stream>>>(h, W, deg_out_f, x, N);
    {
      long long nthreads = (long long)N * 16;
      int blocks = (int)((nthreads + 255) / 256);
      spmm_fused_kernel<<<blocks, 256, 0, stream>>>(row_start, csr_src, x, b, out, N);
    }
  }
}

// Round 4
// 1182.174 us; speedup vs baseline: 1.1124x; 1.1124x over previous
//
// ============================================================================
// Round 4: atomic-free CSR build via privatized LDS histograms + counting sort.
//
// Measured R3: 1315 us. degree_kernel x3 = 441 us: WRITE 99.6 MB = 3.2M
// atomics x 32B line write-through at ~678 GB/s (VALUBusy 0.3%) -- random
// isolated atomics pay a full dirty sector each. scan (single-block, 260
// barriers) and fill (1.6M cursor atomics) share the disease; spmm/gemm/fill
// each < 147 us (below top-5 cutoff).
//
// Change:
//  - hist_kernel: 32 chunks x 4 ranges (12544 bins, 49KB LDS), LDS atomics
//    only, coalesced flush to partials P[chunk][bin]. Run once for src
//    (reduce -> deg_out_f) and once for dst.
//  - b1/b2/offsets: per-bin totals + hierarchical exclusive scan -> row_start,
//    and running per-chunk offsets Off[chunk][bin] (counting-sort bases).
//  - fill_csr: per-(chunk,range) block loads its Off slice into LDS cursors;
//    only LDS atomics + scattered csr stores. Zero global atomics anywhere.
//  - memsets all gone: every buffer fully rewritten; spmm(g=0) writes out.
//  - ws aliasing: x (12.8MB) overlays P+Off (12.85MB) -- both dead before
//    gemm. Total ws ~19.9MB < 26MB proven safe in R1.
//
// Predicted: degree/scan/fill/memset dispatches vanish; hist ~12us each,
// fill_csr ~30-45us (scattered csr write-through is the remaining writer),
// gemm 55us, spmm 60-110us now visible. Total -> ~600-750us.
// ============================================================================
#include <hip/hip_runtime.h>

#define KDIM 128
#define NCOLS 64
#define NCHUNK 32
#define NRANGE 4
#define RBINS 12544                   // bins per range (49 KB LDS)
#define NBINS (NRANGE * RBINS)        // 50176 >= N = 50000
#define SCANB (NBINS / 256)           // 196 scan blocks

// ---------------- partial histogram: P[chunk*NBINS + bin] -------------------
__global__ __launch_bounds__(256) void hist_kernel(
    const int* __restrict__ keys, int* __restrict__ P, int E, int per_chunk) {
  __shared__ int hist[RBINS];
  const int chunk = blockIdx.x;
  const int base  = blockIdx.y * RBINS;
  const int t = threadIdx.x;
  for (int i = t; i < RBINS; i += 256) hist[i] = 0;
  __syncthreads();
  const int e0 = chunk * per_chunk;
  const int e1 = min(e0 + per_chunk, E);
  for (int e = e0 + t; e < e1; e += 256) {
    unsigned k = (unsigned)(keys[e] - base);
    if (k < (unsigned)RBINS) atomicAdd(&hist[k], 1);
  }
  __syncthreads();
  int* dst = P + (size_t)chunk * NBINS + base;
  for (int i = t; i < RBINS; i += 256) dst[i] = hist[i];
}

// ---------------- deg_out_f[bin] = sum_c P[c][bin] (as float) ---------------
__global__ __launch_bounds__(256) void reduce_deg_f_kernel(
    const int* __restrict__ P, float* __restrict__ deg_f) {
  int bin = blockIdx.x * 256 + threadIdx.x;
  int s = 0;
  #pragma unroll
  for (int c = 0; c < NCHUNK; ++c) s += P[(size_t)c * NBINS + bin];
  deg_f[bin] = (float)s;
}

// ---------------- b1: deg_in[bin] = total; block_tot[blk] = sum -------------
__global__ __launch_bounds__(256) void b1_kernel(
    const int* __restrict__ P, int* __restrict__ deg_in,
    int* __restrict__ block_tot) {
  __shared__ int sd[256];
  const int t = threadIdx.x;
  const int bin = blockIdx.x * 256 + t;
  int s = 0;
  #pragma unroll
  for (int c = 0; c < NCHUNK; ++c) s += P[(size_t)c * NBINS + bin];
  deg_in[bin] = s;
  sd[t] = s;
  __syncthreads();
  for (int off = 128; off > 0; off >>= 1) {
    if (t < off) sd[t] += sd[t + off];
    __syncthreads();
  }
  if (t == 0) block_tot[blockIdx.x] = sd[0];
}

// ---------------- b2: exclusive scan of 196 block totals --------------------
__global__ __launch_bounds__(256) void b2_kernel(
    const int* __restrict__ block_tot, int* __restrict__ block_base) {
  __shared__ int sd[256];
  const int t = threadIdx.x;
  int v = (t < SCANB) ? block_tot[t] : 0;
  sd[t] = v;
  __syncthreads();
  for (int off = 1; off < 256; off <<= 1) {
    int add = (t >= off) ? sd[t - off] : 0;
    __syncthreads();
    sd[t] += add;
    __syncthreads();
  }
  if (t < SCANB) block_base[t] = sd[t] - v;
}

// ---------------- offsets: row_start[bin], Off[c][bin] ----------------------
__global__ __launch_bounds__(256) void offsets_kernel(
    const int* __restrict__ P, const int* __restrict__ deg_in,
    const int* __restrict__ block_base, int* __restrict__ row_start,
    int* __restrict__ Off) {
  __shared__ int sd[256];
  const int t = threadIdx.x;
  const int bin = blockIdx.x * 256 + t;
  const int d = deg_in[bin];
  sd[t] = d;
  __syncthreads();
  for (int off = 1; off < 256; off <<= 1) {
    int add = (t >= off) ? sd[t - off] : 0;
    __syncthreads();
    sd[t] += add;
    __syncthreads();
  }
  int run = block_base[blockIdx.x] + sd[t] - d;  // exclusive prefix over bins
  row_start[bin] = run;
  #pragma unroll
  for (int c = 0; c < NCHUNK; ++c) {
    Off[(size_t)c * NBINS + bin] = run;
    run += P[(size_t)c * NBINS + bin];
  }
}

// ---------------- fill: counting sort, LDS cursors only ---------------------
__global__ __launch_bounds__(256) void fill_csr_kernel(
    const int* __restrict__ src, const int* __restrict__ dst,
    const int* __restrict__ Off, int* __restrict__ csr_src,
    int E, int per_chunk) {
  __shared__ int cur[RBINS];
  const int chunk = blockIdx.x;
  const int base  = blockIdx.y * RBINS;
  const int t = threadIdx.x;
  const int* off_row = Off + (size_t)chunk * NBINS + base;
  for (int i = t; i < RBINS; i += 256) cur[i] = off_row[i];
  __syncthreads();
  const int e0 = chunk * per_chunk;
  const int e1 = min(e0 + per_chunk, E);
  for (int e = e0 + t; e < e1; e += 256) {
    unsigned k = (unsigned)(dst[e] - base);
    if (k < (unsigned)RBINS) {
      int pos = atomicAdd(&cur[k], 1);   // LDS atomic: position unique
      csr_src[pos] = src[e];
    }
  }
}

// ---------------- x = (h @ W) * rsqrt(max(deg_out,1)) -----------------------
__device__ __forceinline__ void fma4(float4& a, float s, const float4& b) {
  a.x = fmaf(s, b.x, a.x);
  a.y = fmaf(s, b.y, a.y);
  a.z = fmaf(s, b.z, a.z);
  a.w = fmaf(s, b.w, a.w);
}

__global__ __launch_bounds__(256) void gemm_scale_kernel(
    const float* __restrict__ h, const float* __restrict__ W,
    const float* __restrict__ deg_out, float* __restrict__ x, int N) {
  __shared__ float Ws[KDIM * NCOLS];
  __shared__ float Hs[64][KDIM + 4];

  const int t = threadIdx.x;
  const int tx = t & 15;
  const int ty = t >> 4;
  const int row0 = blockIdx.x * 64;

  #pragma unroll
  for (int i = 0; i < 8; ++i) {
    int lin = i * 1024 + t * 4;
    *(float4*)&Ws[lin] = *(const float4*)&W[lin];
  }
  #pragma unroll
  for (int i = 0; i < 8; ++i) {
    int lin = i * 1024 + t * 4;
    int r = lin >> 7;
    int k = lin & 127;
    int row = row0 + r;
    float4 v = make_float4(0.f, 0.f, 0.f, 0.f);
    if (row < N) v = *(const float4*)&h[(size_t)row * KDIM + k];
    *(float4*)&Hs[r][k] = v;
  }
  __syncthreads();

  float4 acc0 = make_float4(0,0,0,0), acc1 = acc0, acc2 = acc0, acc3 = acc0;
  #pragma unroll 4
  for (int k = 0; k < KDIM; k += 4) {
    float4 a0 = *(float4*)&Hs[4 * ty + 0][k];
    float4 a1 = *(float4*)&Hs[4 * ty + 1][k];
    float4 a2 = *(float4*)&Hs[4 * ty + 2][k];
    float4 a3 = *(float4*)&Hs[4 * ty + 3][k];
    float4 w0 = *(float4*)&Ws[(k + 0) * NCOLS + 4 * tx];
    float4 w1 = *(float4*)&Ws[(k + 1) * NCOLS + 4 * tx];
    float4 w2 = *(float4*)&Ws[(k + 2) * NCOLS + 4 * tx];
    float4 w3 = *(float4*)&Ws[(k + 3) * NCOLS + 4 * tx];
    fma4(acc0, a0.x, w0); fma4(acc0, a0.y, w1); fma4(acc0, a0.z, w2); fma4(acc0, a0.w, w3);
    fma4(acc1, a1.x, w0); fma4(acc1, a1.y, w1); fma4(acc1, a1.z, w2); fma4(acc1, a1.w, w3);
    fma4(acc2, a2.x, w0); fma4(acc2, a2.y, w1); fma4(acc2, a2.z, w2); fma4(acc2, a2.w, w3);
    fma4(acc3, a3.x, w0); fma4(acc3, a3.y, w1); fma4(acc3, a3.z, w2); fma4(acc3, a3.w, w3);
  }

  float4 accs[4] = {acc0, acc1, acc2, acc3};
  #pragma unroll
  for (int r = 0; r < 4; ++r) {
    int row = row0 + 4 * ty + r;
    if (row < N) {
      float s = rsqrtf(fmaxf(deg_out[row], 1.0f));
      float4 o;
      o.x = accs[r].x * s; o.y = accs[r].y * s;
      o.z = accs[r].z * s; o.w = accs[r].w * s;
      *(float4*)&x[(size_t)row * NCOLS + 4 * tx] = o;
    }
  }
}

// ---------------- fused SpMM gather + finalize ------------------------------
__global__ __launch_bounds__(256) void spmm_fused_kernel(
    const int* __restrict__ row_start, const int* __restrict__ csr_src,
    const float* __restrict__ x, const float* __restrict__ b,
    float* __restrict__ out, int N, int init) {
  int gid = blockIdx.x * 256 + threadIdx.x;
  int d = gid >> 4;
  int q = (gid & 15) * 4;
  if (d >= N) return;
  int i = row_start[d];
  const int iend = row_start[d + 1];
  const int deg = iend - i;

  float4 acc = make_float4(0.f, 0.f, 0.f, 0.f);
  for (; i + 3 < iend; i += 4) {
    int sa = csr_src[i + 0];
    int sb = csr_src[i + 1];
    int sc = csr_src[i + 2];
    int sd = csr_src[i + 3];
    float4 va = *(const float4*)&x[(size_t)sa * NCOLS + q];
    float4 vb = *(const float4*)&x[(size_t)sb * NCOLS + q];
    float4 vc = *(const float4*)&x[(size_t)sc * NCOLS + q];
    float4 vd = *(const float4*)&x[(size_t)sd * NCOLS + q];
    acc.x += va.x + vb.x + vc.x + vd.x;
    acc.y += va.y + vb.y + vc.y + vd.y;
    acc.z += va.z + vb.z + vc.z + vd.z;
    acc.w += va.w + vb.w + vc.w + vd.w;
  }
  for (; i < iend; ++i) {
    int s = csr_src[i];
    float4 v = *(const float4*)&x[(size_t)s * NCOLS + q];
    acc.x += v.x; acc.y += v.y; acc.z += v.z; acc.w += v.w;
  }

  float sc = rsqrtf(fmaxf((float)deg, 1.0f));
  float4 bb = *(const float4*)&b[q];
  float4 cur = init ? make_float4(0.f, 0.f, 0.f, 0.f)
                    : *(float4*)&out[(size_t)d * NCOLS + q];
  cur.x += fmaxf(fmaf(acc.x, sc, bb.x), 0.f) * (1.0f / 3.0f);
  cur.y += fmaxf(fmaf(acc.y, sc, bb.y), 0.f) * (1.0f / 3.0f);
  cur.z += fmaxf(fmaf(acc.z, sc, bb.z), 0.f) * (1.0f / 3.0f);
  cur.w += fmaxf(fmaf(acc.w, sc, bb.w), 0.f) * (1.0f / 3.0f);
  *(float4*)&out[(size_t)d * NCOLS + q] = cur;
}

extern "C" void kernel_launch(void* const* d_in, const int* in_sizes, int n_in,
                              void* d_out, int out_size, void* d_ws, size_t ws_size,
                              hipStream_t stream) {
  const float* h = (const float*)d_in[0];
  const int N = in_sizes[0] / KDIM;   // 50000
  float* out = (float*)d_out;

  // ws layout. region1 (12.85MB): P (6.42MB) + Off (6.42MB) during CSR build;
  // aliased by x (12.8MB) during gemm/spmm (P/Off dead by then).
  const size_t pn = (size_t)NCHUNK * NBINS;                 // ints in P / Off
  const size_t region1 = 2 * pn * sizeof(int);              // >= N*64*4
  char* w = (char*)d_ws;
  int*   P         = (int*)w;
  int*   Off       = P + pn;
  float* x         = (float*)w;
  char*  w2        = w + region1;
  int*   csr_src   = (int*)w2;                              // E ints (6.4MB)
  // assume all graphs have same E; use max to be safe
  int Emax = 0;
  for (int g = 0; g < 3; ++g) if (in_sizes[1 + g * 4] > Emax) Emax = in_sizes[1 + g * 4];
  float* deg_out_f = (float*)(csr_src + Emax);              // NBINS floats
  int*   deg_in    = (int*)(deg_out_f + NBINS);             // NBINS ints
  int*   row_start = deg_in + NBINS;                        // NBINS ints
  int*   block_tot = row_start + NBINS;                     // SCANB ints
  int*   block_base= block_tot + SCANB;                     // SCANB ints

  for (int g = 0; g < 3; ++g) {
    const int*   src = (const int*)  d_in[1 + g * 4];
    const int*   dst = (const int*)  d_in[2 + g * 4];
    const float* W   = (const float*)d_in[3 + g * 4];
    const float* b   = (const float*)d_in[4 + g * 4];
    const int E = in_sizes[1 + g * 4];
    const int per_chunk = (E + NCHUNK - 1) / NCHUNK;

    hist_kernel<<<dim3(NCHUNK, NRANGE), 256, 0, stream>>>(src, P, E, per_chunk);
    reduce_deg_f_kernel<<<SCANB, 256, 0, stream>>>(P, deg_out_f);
    hist_kernel<<<dim3(NCHUNK, NRANGE), 256, 0, stream>>>(dst, P, E, per_chunk);
    b1_kernel<<<SCANB, 256, 0, stream>>>(P, deg_in, block_tot);
    b2_kernel<<<1, 256, 0, stream>>>(block_tot, block_base);
    offsets_kernel<<<SCANB, 256, 0, stream>>>(P, deg_in, block_base, row_start, Off);
    fill_csr_kernel<<<dim3(NCHUNK, NRANGE), 256, 0, stream>>>(src, dst, Off, csr_src, E, per_chunk);
    gemm_scale_kernel<<<(N + 63) / 64, 256, 0, stream>>>(h, W, deg_out_f, x, N);
    {
      long long nthreads = (long long)N * 16;
      int blocks = (int)((nthreads + 255) / 256);
      spmm_fused_kernel<<<blocks, 256, 0, stream>>>(row_start, csr_src, x, b, out, N, g == 0 ? 1 : 0);
    }
  }
}

// Round 5
// 700.343 us; speedup vs baseline: 1.8777x; 1.6880x over previous
//
// ============================================================================
// Round 5: two-level dst-bucketing; all fine-grained scatter moved to LDS.
//
// Measured R4: 1182 us. fill_csr x3 = 340 us: WRITE 58.5 MB = 1.6M scattered
// 4B stores x 32B sector write-through (9x amplification; each bin row hit by
// ~32 chunk-blocks on different XCDs), occupancy 5% (grid 128). hist(dst) +
// b1/b2/offsets exist only to feed it. gemm 55 us; spmm < 113 us (not top-5).
//
// Change:
//  - count_bucket + scan_bucket + partition: edges -> 261 buckets of 192 dst,
//    pairs (src,dst) written in ~190B runs (per-block LDS count, one global
//    atomicAdd per (block,bucket) to reserve space, LDS cursors).
//  - bucket_spmm: 1 block/bucket, 1024 thr: in-LDS counting sort (~6.1K edges,
//    cap 8192 = mean + 26 sigma), then per-dst 16-lane register accumulate,
//    finalize fused (deg_in = free from LDS counts), coalesced out writes.
//  - deleted: hist(dst), b1, b2, offsets, fill_csr, global csr_src, deg_in.
//  - ws: x (12.8M) aliases src-hist partials P (6.4M, dead pre-gemm);
//    P2 pairs 12.8M; total ~25.8 MB (R1 proved 26 MB safe).
//
// Predicted: fill_csr gone; partition ~30-45us (W 13-20 MB), bucket_spmm
// ~45-65us (gather 102 MB L2/LLC), gemm 55us now top-2. Total -> 650-800us.
// ============================================================================
#include <hip/hip_runtime.h>

#define KDIM 128
#define NCOLS 64
// src-degree histogram (unchanged from R4)
#define NCHUNK 32
#define NRANGE 4
#define RBINS 12544
#define NBINS (NRANGE * RBINS)     // 50176
#define SCANB (NBINS / 256)        // 196
// dst buckets
#define BUCKET 192                 // dst nodes per bucket
#define NBUCK 261                  // ceil(50000/192)
#define MAXBE 8192                 // LDS edge cap per bucket (mean 6144)

// ---------------- coarse bucket count ---------------------------------------
__global__ __launch_bounds__(256) void count_bucket_kernel(
    const int* __restrict__ dst, int* __restrict__ bucket_tot, int E) {
  __shared__ int hist[NBUCK];
  const int t = threadIdx.x;
  for (int i = t; i < NBUCK; i += 256) hist[i] = 0;
  __syncthreads();
  for (int e = blockIdx.x * 256 + t; e < E; e += gridDim.x * 256)
    atomicAdd(&hist[(unsigned)dst[e] / BUCKET], 1);
  __syncthreads();
  for (int i = t; i < NBUCK; i += 256)
    if (hist[i]) atomicAdd(&bucket_tot[i], hist[i]);
}

// ---------------- scan 261 totals -> base[262], cursor[261] -----------------
__global__ __launch_bounds__(512) void scan_bucket_kernel(
    const int* __restrict__ bucket_tot, int* __restrict__ bucket_base,
    int* __restrict__ bucket_cur) {
  __shared__ int sd[512];
  const int t = threadIdx.x;
  int v = (t < NBUCK) ? bucket_tot[t] : 0;
  sd[t] = v;
  __syncthreads();
  for (int off = 1; off < 512; off <<= 1) {
    int add = (t >= off) ? sd[t - off] : 0;
    __syncthreads();
    sd[t] += add;
    __syncthreads();
  }
  int excl = sd[t] - v;
  if (t < NBUCK) { bucket_base[t] = excl; bucket_cur[t] = excl; }
  if (t == 0) bucket_base[NBUCK] = sd[511];
}

// ---------------- partition edges into bucket regions (pairs) ---------------
__global__ __launch_bounds__(256) void partition_kernel(
    const int* __restrict__ src, const int* __restrict__ dst,
    int* __restrict__ bucket_cur, int2* __restrict__ P2, int E, int per_block) {
  __shared__ int lcnt[NBUCK];
  __shared__ int lcur[NBUCK];
  const int t = threadIdx.x;
  const int e0 = blockIdx.x * per_block;
  const int e1 = min(e0 + per_block, E);
  for (int i = t; i < NBUCK; i += 256) lcnt[i] = 0;
  __syncthreads();
  for (int e = e0 + t; e < e1; e += 256)
    atomicAdd(&lcnt[(unsigned)dst[e] / BUCKET], 1);
  __syncthreads();
  for (int i = t; i < NBUCK; i += 256) {
    int c = lcnt[i];
    lcur[i] = c ? atomicAdd(&bucket_cur[i], c) : 0;
  }
  __syncthreads();
  for (int e = e0 + t; e < e1; e += 256) {
    int d = dst[e];
    int pos = atomicAdd(&lcur[(unsigned)d / BUCKET], 1);
    P2[pos] = make_int2(src[e], d);
  }
}

// ---------------- src histogram partials (for deg_out) ----------------------
__global__ __launch_bounds__(256) void hist_kernel(
    const int* __restrict__ keys, int* __restrict__ P, int E, int per_chunk) {
  __shared__ int hist[RBINS];
  const int chunk = blockIdx.x;
  const int base  = blockIdx.y * RBINS;
  const int t = threadIdx.x;
  for (int i = t; i < RBINS; i += 256) hist[i] = 0;
  __syncthreads();
  const int e0 = chunk * per_chunk;
  const int e1 = min(e0 + per_chunk, E);
  for (int e = e0 + t; e < e1; e += 256) {
    unsigned k = (unsigned)(keys[e] - base);
    if (k < (unsigned)RBINS) atomicAdd(&hist[k], 1);
  }
  __syncthreads();
  int* dstp = P + (size_t)chunk * NBINS + base;
  for (int i = t; i < RBINS; i += 256) dstp[i] = hist[i];
}

__global__ __launch_bounds__(256) void reduce_deg_f_kernel(
    const int* __restrict__ P, float* __restrict__ deg_f) {
  int bin = blockIdx.x * 256 + threadIdx.x;
  int s = 0;
  #pragma unroll
  for (int c = 0; c < NCHUNK; ++c) s += P[(size_t)c * NBINS + bin];
  deg_f[bin] = (float)s;
}

// ---------------- x = (h @ W) * rsqrt(max(deg_out,1)) -----------------------
__device__ __forceinline__ void fma4(float4& a, float s, const float4& b) {
  a.x = fmaf(s, b.x, a.x);
  a.y = fmaf(s, b.y, a.y);
  a.z = fmaf(s, b.z, a.z);
  a.w = fmaf(s, b.w, a.w);
}

__global__ __launch_bounds__(256) void gemm_scale_kernel(
    const float* __restrict__ h, const float* __restrict__ W,
    const float* __restrict__ deg_out, float* __restrict__ x, int N) {
  __shared__ float Ws[KDIM * NCOLS];
  __shared__ float Hs[64][KDIM + 4];

  const int t = threadIdx.x;
  const int tx = t & 15;
  const int ty = t >> 4;
  const int row0 = blockIdx.x * 64;

  #pragma unroll
  for (int i = 0; i < 8; ++i) {
    int lin = i * 1024 + t * 4;
    *(float4*)&Ws[lin] = *(const float4*)&W[lin];
  }
  #pragma unroll
  for (int i = 0; i < 8; ++i) {
    int lin = i * 1024 + t * 4;
    int r = lin >> 7;
    int k = lin & 127;
    int row = row0 + r;
    float4 v = make_float4(0.f, 0.f, 0.f, 0.f);
    if (row < N) v = *(const float4*)&h[(size_t)row * KDIM + k];
    *(float4*)&Hs[r][k] = v;
  }
  __syncthreads();

  float4 acc0 = make_float4(0,0,0,0), acc1 = acc0, acc2 = acc0, acc3 = acc0;
  #pragma unroll 4
  for (int k = 0; k < KDIM; k += 4) {
    float4 a0 = *(float4*)&Hs[4 * ty + 0][k];
    float4 a1 = *(float4*)&Hs[4 * ty + 1][k];
    float4 a2 = *(float4*)&Hs[4 * ty + 2][k];
    float4 a3 = *(float4*)&Hs[4 * ty + 3][k];
    float4 w0 = *(float4*)&Ws[(k + 0) * NCOLS + 4 * tx];
    float4 w1 = *(float4*)&Ws[(k + 1) * NCOLS + 4 * tx];
    float4 w2 = *(float4*)&Ws[(k + 2) * NCOLS + 4 * tx];
    float4 w3 = *(float4*)&Ws[(k + 3) * NCOLS + 4 * tx];
    fma4(acc0, a0.x, w0); fma4(acc0, a0.y, w1); fma4(acc0, a0.z, w2); fma4(acc0, a0.w, w3);
    fma4(acc1, a1.x, w0); fma4(acc1, a1.y, w1); fma4(acc1, a1.z, w2); fma4(acc1, a1.w, w3);
    fma4(acc2, a2.x, w0); fma4(acc2, a2.y, w1); fma4(acc2, a2.z, w2); fma4(acc2, a2.w, w3);
    fma4(acc3, a3.x, w0); fma4(acc3, a3.y, w1); fma4(acc3, a3.z, w2); fma4(acc3, a3.w, w3);
  }

  float4 accs[4] = {acc0, acc1, acc2, acc3};
  #pragma unroll
  for (int r = 0; r < 4; ++r) {
    int row = row0 + 4 * ty + r;
    if (row < N) {
      float s = rsqrtf(fmaxf(deg_out[row], 1.0f));
      float4 o;
      o.x = accs[r].x * s; o.y = accs[r].y * s;
      o.z = accs[r].z * s; o.w = accs[r].w * s;
      *(float4*)&x[(size_t)row * NCOLS + 4 * tx] = o;
    }
  }
}

// ---------------- bucket SpMM: LDS counting sort + register accumulate ------
__global__ __launch_bounds__(1024) void bucket_spmm_kernel(
    const int2* __restrict__ P2, const int* __restrict__ bucket_base,
    const float* __restrict__ x, const float* __restrict__ b,
    float* __restrict__ out, int N, int init) {
  __shared__ int cnt[BUCKET];
  __shared__ int rs[BUCKET + 1];
  __shared__ int cur[BUCKET];
  __shared__ int sd[256];
  __shared__ int srcs[MAXBE];

  const int t = threadIdx.x;
  const int bk = blockIdx.x;
  const int dbase = bk * BUCKET;
  const int nd = min(BUCKET, N - dbase);
  const int e0 = bucket_base[bk];
  const int ne = bucket_base[bk + 1] - e0;

  if (t < BUCKET) cnt[t] = 0;
  __syncthreads();
  for (int i = t; i < ne; i += 1024)
    atomicAdd(&cnt[P2[e0 + i].y - dbase], 1);
  __syncthreads();
  // exclusive scan of cnt[0..191] via 256-wide Hillis-Steele
  int v = 0;
  if (t < 256) { v = (t < BUCKET) ? cnt[t] : 0; sd[t] = v; }
  __syncthreads();
  for (int off = 1; off < 256; off <<= 1) {
    int add = (t < 256 && t >= off) ? sd[t - off] : 0;
    __syncthreads();
    if (t < 256) sd[t] += add;
    __syncthreads();
  }
  if (t < BUCKET) { int ex = sd[t] - v; rs[t] = ex; cur[t] = ex; }
  if (t == BUCKET) rs[BUCKET] = sd[BUCKET - 1];
  __syncthreads();
  // fill sorted srcs
  for (int i = t; i < ne; i += 1024) {
    int2 p = P2[e0 + i];
    int pos = atomicAdd(&cur[p.y - dbase], 1);
    if (pos < MAXBE) srcs[pos] = p.x;
  }
  __syncthreads();
  // per-dst accumulate: 64 groups of 16 lanes
  const int grp = t >> 4;
  const int q = (t & 15) * 4;
  for (int ld = grp; ld < nd; ld += 64) {
    int i = rs[ld];
    const int iend = rs[ld + 1];
    const int deg = iend - i;
    float4 acc = make_float4(0.f, 0.f, 0.f, 0.f);
    for (; i + 3 < iend; i += 4) {
      int sa = srcs[i + 0];
      int sb = srcs[i + 1];
      int sc = srcs[i + 2];
      int sdd = srcs[i + 3];
      float4 va = *(const float4*)&x[(size_t)sa * NCOLS + q];
      float4 vb = *(const float4*)&x[(size_t)sb * NCOLS + q];
      float4 vc = *(const float4*)&x[(size_t)sc * NCOLS + q];
      float4 vd = *(const float4*)&x[(size_t)sdd * NCOLS + q];
      acc.x += va.x + vb.x + vc.x + vd.x;
      acc.y += va.y + vb.y + vc.y + vd.y;
      acc.z += va.z + vb.z + vc.z + vd.z;
      acc.w += va.w + vb.w + vc.w + vd.w;
    }
    for (; i < iend; ++i) {
      int s = srcs[i];
      float4 vv = *(const float4*)&x[(size_t)s * NCOLS + q];
      acc.x += vv.x; acc.y += vv.y; acc.z += vv.z; acc.w += vv.w;
    }
    float sc2 = rsqrtf(fmaxf((float)deg, 1.0f));
    float4 bb = *(const float4*)&b[q];
    int dglob = dbase + ld;
    float4 curo = init ? make_float4(0.f, 0.f, 0.f, 0.f)
                       : *(float4*)&out[(size_t)dglob * NCOLS + q];
    curo.x += fmaxf(fmaf(acc.x, sc2, bb.x), 0.f) * (1.0f / 3.0f);
    curo.y += fmaxf(fmaf(acc.y, sc2, bb.y), 0.f) * (1.0f / 3.0f);
    curo.z += fmaxf(fmaf(acc.z, sc2, bb.z), 0.f) * (1.0f / 3.0f);
    curo.w += fmaxf(fmaf(acc.w, sc2, bb.w), 0.f) * (1.0f / 3.0f);
    *(float4*)&out[(size_t)dglob * NCOLS + q] = curo;
  }
}

extern "C" void kernel_launch(void* const* d_in, const int* in_sizes, int n_in,
                              void* d_out, int out_size, void* d_ws, size_t ws_size,
                              hipStream_t stream) {
  const float* h = (const float*)d_in[0];
  const int N = in_sizes[0] / KDIM;   // 50000
  float* out = (float*)d_out;

  int Emax = 0;
  for (int g = 0; g < 3; ++g) if (in_sizes[1 + g * 4] > Emax) Emax = in_sizes[1 + g * 4];

  // ws: [x: N*64 floats (first 6.42MB aliased by src-hist partials P)]
  //     [P2: Emax int2] [deg_out_f: NBINS] [bucket_tot|base|cur]
  char* w = (char*)d_ws;
  float* x  = (float*)w;
  int*   P  = (int*)w;                       // NCHUNK*NBINS ints, dead pre-gemm
  char*  w2 = w + (size_t)N * NCOLS * sizeof(float);
  int2*  P2 = (int2*)w2;
  char*  w3 = w2 + (size_t)Emax * sizeof(int2);
  float* deg_out_f  = (float*)w3;            // NBINS
  int*   bucket_tot = (int*)(deg_out_f + NBINS);
  int*   bucket_base= bucket_tot + NBUCK;    // NBUCK+1
  int*   bucket_cur = bucket_base + NBUCK + 1;

  for (int g = 0; g < 3; ++g) {
    const int*   src = (const int*)  d_in[1 + g * 4];
    const int*   dst = (const int*)  d_in[2 + g * 4];
    const float* W   = (const float*)d_in[3 + g * 4];
    const float* b   = (const float*)d_in[4 + g * 4];
    const int E = in_sizes[1 + g * 4];
    const int per_chunk = (E + NCHUNK - 1) / NCHUNK;
    const int per_block = (E + 255) / 256;

    hipMemsetAsync(bucket_tot, 0, NBUCK * sizeof(int), stream);
    count_bucket_kernel<<<256, 256, 0, stream>>>(dst, bucket_tot, E);
    scan_bucket_kernel<<<1, 512, 0, stream>>>(bucket_tot, bucket_base, bucket_cur);
    partition_kernel<<<256, 256, 0, stream>>>(src, dst, bucket_cur, P2, E, per_block);
    hist_kernel<<<dim3(NCHUNK, NRANGE), 256, 0, stream>>>(src, P, E, per_chunk);
    reduce_deg_f_kernel<<<SCANB, 256, 0, stream>>>(P, deg_out_f);
    gemm_scale_kernel<<<(N + 63) / 64, 256, 0, stream>>>(h, W, deg_out_f, x, N);
    bucket_spmm_kernel<<<NBUCK, 1024, 0, stream>>>(P2, bucket_base, x, b, out, N, g == 0 ? 1 : 0);
  }
}